// Round 20
// baseline (407.758 us; speedup 1.0000x reference)
//
#include <hip/hip_runtime.h>

#ifndef __has_builtin
#define __has_builtin(x) 0
#endif

#define T_STEPS 512
#define BATCH   128
#define DIN     256
#define HID     256
#define WPLD    (DIN + HID)   // 512

// Volatile asm loads: results are NOT rematerializable.
#define ASM_LOAD4(dst, ptr) \
    asm volatile("global_load_dwordx4 %0, %1, off" : "=v"(dst) : "v"(ptr))
#define ASM_LOAD2(dst, ptr) \
    asm volatile("global_load_dwordx2 %0, %1, off" : "=v"(dst) : "v"(ptr))

// Barrier WITHOUT vmcnt drain (verified R11/R12): waits only LDS ops.
#define STEP_BARRIER() do {                                   \
    asm volatile("s_waitcnt lgkmcnt(0)" ::: "memory");        \
    __builtin_amdgcn_s_barrier();                             \
    __builtin_amdgcn_sched_barrier(0);                        \
} while (0)

// ---------------- cross-lane helpers (verified in passing runs) ----------------
template<int CTRL>
__device__ __forceinline__ float dppmov(float x) {
    // 0xB1=quad xor1, 0x4E=quad xor2, 0x124=row_ror:4, 0x128=row_ror:8
    return __int_as_float(__builtin_amdgcn_update_dpp(0, __float_as_int(x), CTRL, 0xF, 0xF, true));
}
template<int PAT>
__device__ __forceinline__ float swz(float x) {
    return __int_as_float(__builtin_amdgcn_ds_swizzle(__float_as_int(x), PAT));
}
__device__ __forceinline__ float lane_xor16(float v, int l) {
#if __has_builtin(__builtin_amdgcn_permlane16_swap)
    auto r = __builtin_amdgcn_permlane16_swap(__float_as_uint(v), __float_as_uint(v), false, false);
    return __uint_as_float((l & 16) ? r[0] : r[1]);
#else
    return swz<0x401F>(v);
#endif
}
__device__ __forceinline__ float lane_xor32(float v, int l) {
#if __has_builtin(__builtin_amdgcn_permlane32_swap)
    auto r = __builtin_amdgcn_permlane32_swap(__float_as_uint(v), __float_as_uint(v), false, false);
    return __uint_as_float((l & 32) ? r[0] : r[1]);
#else
    return __shfl_xor(v, 32);
#endif
}
__device__ __forceinline__ float rcp_f(float x) {
#if __has_builtin(__builtin_amdgcn_rcpf)
    return __builtin_amdgcn_rcpf(x);
#else
    return 1.0f / x;
#endif
}

// ---------------------------------------------------------------------------
// Kernel 1: px[b][t][q] = sum_d x[t,b,d]*Wp[q,d] + qp[q]   (unchanged, verified)
// ---------------------------------------------------------------------------
__global__ __launch_bounds__(256) void qlstm_projx(const float* __restrict__ x,
                                                   const float* __restrict__ Wp,
                                                   const float* __restrict__ qp,
                                                   float* __restrict__ px) {
    const int wave = threadIdx.x >> 6;
    const int lane = threadIdx.x & 63;
    const int row  = blockIdx.x * 4 + wave;       // row = t*BATCH + b

    const float4 xv = ((const float4*)(x + (size_t)row * DIN))[lane];
    float acc[8];
#pragma unroll
    for (int Q = 0; Q < 8; ++Q) {
        float4 w = ((const float4*)(Wp + Q * WPLD))[lane];
        acc[Q] = xv.x * w.x + xv.y * w.y + xv.z * w.z + xv.w * w.w;
    }
#pragma unroll
    for (int Q = 0; Q < 8; ++Q) {
        acc[Q] += dppmov<0xB1>(acc[Q]);
        acc[Q] += dppmov<0x4E>(acc[Q]);
        acc[Q] += swz<0x101F>(acc[Q]);
    }
    float p = acc[0];
#pragma unroll
    for (int j = 1; j < 8; ++j) p = ((lane & 7) == j) ? acc[j] : p;
    p += swz<0x201F>(p);
    p += swz<0x401F>(p);
    p += __shfl_xor(p, 32);
    if (lane < 8) {
        const int bb = row & (BATCH - 1);
        const int tt = row >> 7;
        px[(size_t)bb * (T_STEPS * 8) + tt * 8 + lane] = p + qp[lane];
    }
}

// ---------------------------------------------------------------------------
// Kernel 2: recurrence. TWO waves per row (128 threads); wave w owns columns
// [w*128, w*128+128), lane l owns cols cg0=w*128+2l, cg1=cg0+1 — h NEVER
// leaves registers. Per step: partial dots (2 fma per q) over own columns ->
// 8 verified all-VALU allreduce chains -> lane0 publishes 8 partial sums ->
// ONE 2-wave barrier -> read other wave's 8 partials (broadcast f4 reads) ->
// full sums + px -> 8 cos -> prefix -> gates/LSTM for 2 columns -> f2 store.
// part[] double-buffered so the single barrier separates read from overwrite
// (race pattern verified R15/R16).
// ---------------------------------------------------------------------------
__global__ __launch_bounds__(128, 1) void qlstm_seq(const float* __restrict__ hx,
                                                    const float* __restrict__ cx,
                                                    const float* __restrict__ Wp,
                                                    const float* __restrict__ Wg,
                                                    const float* __restrict__ bg,
                                                    const float* __restrict__ px,
                                                    float* __restrict__ out) {
    __shared__ float px_lds[(T_STEPS + 1) * 8];   // +8 pad for prefetch overrun
    __shared__ float part[2][2][8];               // [buf][wave][q] partial sums

    const int tid = threadIdx.x;
    const int w   = tid >> 6;      // wave id 0..1
    const int l   = tid & 63;      // lane
    const int b   = blockIdx.x;
    const int cg0 = (w << 7) + 2 * l;   // this lane's two columns
    // cg1 = cg0 + 1

    // ---- weight loads (asm: non-rematerializable) ----
    float2 wph[8];                 // Wp[q][256+cg0 .. +1]
#pragma unroll
    for (int q = 0; q < 8; ++q) {
        const float* a = Wp + q * WPLD + DIN + cg0;
        ASM_LOAD2(wph[q], a);
    }
    // Wg rows for col cg0 and cg1: [G][col][half]
    float4 WGa[4][2], WGb[4][2];   // a=col0, b=col1
#pragma unroll
    for (int G = 0; G < 4; ++G) {
        const float* r0 = Wg + (size_t)(G * HID + cg0) * 8;
        ASM_LOAD4(WGa[G][0], r0);
        ASM_LOAD4(WGa[G][1], r0 + 4);
        ASM_LOAD4(WGb[G][0], r0 + 8);
        ASM_LOAD4(WGb[G][1], r0 + 12);
    }
    float2 bgc[4];                 // bg[G*256+cg0 .. +1]
#pragma unroll
    for (int G = 0; G < 4; ++G) {
        const float* a = bg + G * HID + cg0;
        ASM_LOAD2(bgc[G], a);
    }

    // preload all px for this b (4096 floats = 1024 float4, 8 per thread)
    {
        const float4* pg = (const float4*)(px + (size_t)b * (T_STEPS * 8));
        float4* pl = (float4*)px_lds;
#pragma unroll
        for (int j = 0; j < 8; ++j) pl[j * 128 + tid] = pg[j * 128 + tid];
    }

    float2 hv = *(const float2*)(hx + b * HID + cg0);
    float2 cv = *(const float2*)(cx + b * HID + cg0);

    asm volatile("s_waitcnt vmcnt(0)" ::: "memory");
    __builtin_amdgcn_sched_barrier(0);
    __syncthreads();   // px_lds ready (prologue only)

    // prefetch px[t=0][0..7]
    float4 pxa = *(const float4*)(&px_lds[0]);
    float4 pxb = *(const float4*)(&px_lds[4]);

    float* outp = out + (size_t)b * HID + cg0;

    for (int t = 0; t < T_STEPS; ++t) {
        // ---- phase A: partial dots over own 2 columns + 8 allreduce chains ----
        float s[8];
#pragma unroll
        for (int q = 0; q < 8; ++q) {
            s[q] = fmaf(hv.y, wph[q].y, hv.x * wph[q].x);
        }
#pragma unroll
        for (int q = 0; q < 8; ++q) {
            float v = s[q];
            v += dppmov<0xB1>(v);        // xor1   (DPP)
            v += dppmov<0x4E>(v);        // xor2   (DPP)
            v += dppmov<0x124>(v);       // ror4   (DPP)
            v += dppmov<0x128>(v);       // ror8   (DPP)
            v += lane_xor16(v, l);       // permlane16_swap
            v += lane_xor32(v, l);       // permlane32_swap
            s[q] = v;                    // full sum over this wave's 128 cols
        }
        // lane 0 publishes this wave's 8 partial sums
        if (l == 0) {
            *(float4*)&part[t & 1][w][0] = make_float4(s[0], s[1], s[2], s[3]);
            *(float4*)&part[t & 1][w][4] = make_float4(s[4], s[5], s[6], s[7]);
        }
        STEP_BARRIER();   // the ONLY barrier per step (2 waves, minimal skew)

        // ---- phase B: combine with other wave's partials, cos, gates, LSTM ----
        const float4 o0 = *(const float4*)&part[t & 1][1 - w][0];
        const float4 o1 = *(const float4*)&part[t & 1][1 - w][4];

        const float C0 = __cosf(s[0] + o0.x + pxa.x);
        const float C1 = __cosf(s[1] + o0.y + pxa.y);
        const float C2 = __cosf(s[2] + o0.z + pxa.z);
        const float C3 = __cosf(s[3] + o0.w + pxa.w);
        const float C4 = __cosf(s[4] + o1.x + pxb.x);
        const float C5 = __cosf(s[5] + o1.y + pxb.y);
        const float C6 = __cosf(s[6] + o1.z + pxb.z);
        const float C7 = __cosf(s[7] + o1.w + pxb.w);

        // prefetch px for t+1 (off critical path)
        pxa = *(const float4*)(&px_lds[(t + 1) * 8]);
        pxb = *(const float4*)(&px_lds[(t + 1) * 8 + 4]);

        // prefix products: qo[0]=C1..C7, qo[k>=1]=C0..Ck
        const float d01 = C0 * C1, d23 = C2 * C3, d45 = C4 * C5, d67 = C6 * C7;
        float qo[8];
        qo[1] = d01;
        qo[2] = d01 * C2;
        qo[3] = d01 * d23;
        qo[4] = qo[3] * C4;
        qo[5] = qo[3] * d45;
        qo[6] = qo[5] * C6;
        qo[7] = qo[5] * d67;
        qo[0] = (C1 * d23) * (d45 * d67);

        // gates for the two columns (tree-structured, scalar fma)
        float ga[4], gb[4];
#pragma unroll
        for (int G = 0; G < 4; ++G) {
            float a0, a1;
            a0 = fmaf(WGa[G][0].x, qo[0], bgc[G].x);  a0 = fmaf(WGa[G][0].y, qo[1], a0);
            a0 = fmaf(WGa[G][0].z, qo[2], a0);        a0 = fmaf(WGa[G][0].w, qo[3], a0);
            a1 = WGa[G][1].x * qo[4];                 a1 = fmaf(WGa[G][1].y, qo[5], a1);
            a1 = fmaf(WGa[G][1].z, qo[6], a1);        a1 = fmaf(WGa[G][1].w, qo[7], a1);
            ga[G] = a0 + a1;
            a0 = fmaf(WGb[G][0].x, qo[0], bgc[G].y);  a0 = fmaf(WGb[G][0].y, qo[1], a0);
            a0 = fmaf(WGb[G][0].z, qo[2], a0);        a0 = fmaf(WGb[G][0].w, qo[3], a0);
            a1 = WGb[G][1].x * qo[4];                 a1 = fmaf(WGb[G][1].y, qo[5], a1);
            a1 = fmaf(WGb[G][1].z, qo[6], a1);        a1 = fmaf(WGb[G][1].w, qo[7], a1);
            gb[G] = a0 + a1;
        }

        // LSTM pointwise (inf-safe parallel form, as R12/R19), per column
        {
            const float sf = rcp_f(1.f + __expf(-ga[0]));
            const float si = rcp_f(1.f + __expf(-ga[1]));
            const float so = rcp_f(1.f + __expf(-ga[3]));
            const float tg = 1.f - 2.f * rcp_f(__expf(2.f * ga[2]) + 1.f);
            const float cn = fmaf(sf, cv.x, si * tg);
            const float th = 1.f - 2.f * rcp_f(__expf(2.f * cn) + 1.f);
            hv.x = so * th;
            cv.x = cn;
        }
        {
            const float sf = rcp_f(1.f + __expf(-gb[0]));
            const float si = rcp_f(1.f + __expf(-gb[1]));
            const float so = rcp_f(1.f + __expf(-gb[3]));
            const float tg = 1.f - 2.f * rcp_f(__expf(2.f * gb[2]) + 1.f);
            const float cn = fmaf(sf, cv.y, si * tg);
            const float th = 1.f - 2.f * rcp_f(__expf(2.f * cn) + 1.f);
            hv.y = so * th;
            cv.y = cn;
        }

        *(float2*)outp = hv;         // coalesced 8B store; not drained at barrier
        outp += BATCH * HID;
    }

    const size_t base = (size_t)T_STEPS * BATCH * HID;
    *(float2*)(out + base + b * HID + cg0) = hv;
    *(float2*)(out + base + BATCH * HID + b * HID + cg0) = cv;
}

extern "C" void kernel_launch(void* const* d_in, const int* in_sizes, int n_in,
                              void* d_out, int out_size, void* d_ws, size_t ws_size,
                              hipStream_t stream) {
    const float* x   = (const float*)d_in[0];   // (512,128,256)
    const float* hx  = (const float*)d_in[1];   // (128,256)
    const float* cx  = (const float*)d_in[2];   // (128,256)
    const float* Wp  = (const float*)d_in[3];   // (8,512)
    const float* qp  = (const float*)d_in[4];   // (8,)
    const float* Wg  = (const float*)d_in[5];   // (1024,8)
    const float* bg  = (const float*)d_in[6];   // (1024,)
    float* out = (float*)d_out;
    float* px  = (float*)d_ws;                  // 128*512*8 floats = 2 MB

    qlstm_projx<<<(T_STEPS * BATCH) / 4, 256, 0, stream>>>(x, Wp, qp, px);
    qlstm_seq<<<BATCH, 128, 0, stream>>>(hx, cx, Wp, Wg, bg, px, out);
}

// Round 22
// 297.270 us; speedup vs baseline: 1.3717x; 1.3717x over previous
//
#include <hip/hip_runtime.h>

#ifndef __has_builtin
#define __has_builtin(x) 0
#endif

#define T_STEPS 512
#define BATCH   128
#define DIN     256
#define HID     256
#define WPLD    (DIN + HID)   // 512

// Volatile asm loads: results are NOT rematerializable.
#define ASM_LOAD4(dst, ptr) \
    asm volatile("global_load_dwordx4 %0, %1, off" : "=v"(dst) : "v"(ptr))
#define ASM_LOAD1(dst, ptr) \
    asm volatile("global_load_dword %0, %1, off" : "=v"(dst) : "v"(ptr))

// Barrier WITHOUT vmcnt drain (verified R11/R12): waits only LDS ops.
#define STEP_BARRIER() do {                                   \
    asm volatile("s_waitcnt lgkmcnt(0)" ::: "memory");        \
    __builtin_amdgcn_s_barrier();                             \
    __builtin_amdgcn_sched_barrier(0);                        \
} while (0)

// ---------------- cross-lane helpers (verified in passing runs) ----------------
template<int CTRL>
__device__ __forceinline__ float dppmov(float x) {
    // 0xB1=quad xor1, 0x4E=quad xor2, 0x124=row_ror:4, 0x128=row_ror:8,
    // 0x12C=row_ror:12. row_ror:N => lane i READS lane (i-N)%16 (values move
    // toward higher lanes). ror8 is self-inverse == exact xor8 permute.
    return __int_as_float(__builtin_amdgcn_update_dpp(0, __float_as_int(x), CTRL, 0xF, 0xF, true));
}
template<int PAT>
__device__ __forceinline__ float swz(float x) {
    return __int_as_float(__builtin_amdgcn_ds_swizzle(__float_as_int(x), PAT));
}
__device__ __forceinline__ float lane_xor16(float v, int l) {
#if __has_builtin(__builtin_amdgcn_permlane16_swap)
    auto r = __builtin_amdgcn_permlane16_swap(__float_as_uint(v), __float_as_uint(v), false, false);
    return __uint_as_float((l & 16) ? r[0] : r[1]);
#else
    return swz<0x401F>(v);
#endif
}
__device__ __forceinline__ float lane_xor32(float v, int l) {
#if __has_builtin(__builtin_amdgcn_permlane32_swap)
    auto r = __builtin_amdgcn_permlane32_swap(__float_as_uint(v), __float_as_uint(v), false, false);
    return __uint_as_float((l & 32) ? r[0] : r[1]);
#else
    return __shfl_xor(v, 32);
#endif
}
// xor4 partner value, pure VALU. row_ror:N reads lane (i-N)%16, so:
//   (l&4)==1 lanes (partner l-4): ror4 reads (l-4) = l^4  ✓
//   (l&4)==0 lanes (partner l+4): ror12 reads (l-12)%16 = (l+4)%16 = l^4 ✓
// (R21 had this select inverted — the round's sole failure cause.)
__device__ __forceinline__ float lane_xor4(float v, int l) {
    const float a = dppmov<0x124>(v);   // reads (i-4)%16
    const float b = dppmov<0x12C>(v);   // reads (i-12)%16 == (i+4)%16
    return (l & 4) ? a : b;             // == v @ (l^4)
}
__device__ __forceinline__ float rcp_f(float x) {
#if __has_builtin(__builtin_amdgcn_rcpf)
    return __builtin_amdgcn_rcpf(x);
#else
    return 1.0f / x;
#endif
}

// ---------------------------------------------------------------------------
// Kernel 1: px[b][t][q] = sum_d x[t,b,d]*Wp[q,d] + qp[q]   (unchanged, verified)
// ---------------------------------------------------------------------------
__global__ __launch_bounds__(256) void qlstm_projx(const float* __restrict__ x,
                                                   const float* __restrict__ Wp,
                                                   const float* __restrict__ qp,
                                                   float* __restrict__ px) {
    const int wave = threadIdx.x >> 6;
    const int lane = threadIdx.x & 63;
    const int row  = blockIdx.x * 4 + wave;       // row = t*BATCH + b

    const float4 xv = ((const float4*)(x + (size_t)row * DIN))[lane];
    float acc[8];
#pragma unroll
    for (int Q = 0; Q < 8; ++Q) {
        float4 w = ((const float4*)(Wp + Q * WPLD))[lane];
        acc[Q] = xv.x * w.x + xv.y * w.y + xv.z * w.z + xv.w * w.w;
    }
#pragma unroll
    for (int Q = 0; Q < 8; ++Q) {
        acc[Q] += dppmov<0xB1>(acc[Q]);
        acc[Q] += dppmov<0x4E>(acc[Q]);
        acc[Q] += swz<0x101F>(acc[Q]);
    }
    float p = acc[0];
#pragma unroll
    for (int j = 1; j < 8; ++j) p = ((lane & 7) == j) ? acc[j] : p;
    p += swz<0x201F>(p);
    p += swz<0x401F>(p);
    p += __shfl_xor(p, 32);
    if (lane < 8) {
        const int bb = row & (BATCH - 1);
        const int tt = row >> 7;
        px[(size_t)bb * (T_STEPS * 8) + tt * 8 + lane] = p + qp[lane];
    }
}

// ---------------------------------------------------------------------------
// Kernel 2: recurrence. 4 waves, lane owns ONE column (cg=tid); h in register.
// Phase A: p[q]=h*wph[q] (8 mul) -> split-butterfly reduce-scatter:
//   xor32 (keep 4 of 8 values), xor16 (2), xor8 via ror8 (1) -> lane l holds
//   partial for q=l>>3 over lanes {k: k==l mod 8}; then symmetric butterfly
//   xor1,xor2 (quad DPP) + xor4 (ror4/ror12+sel, FIXED direction) completes
//   the 64-lane sum. All VALU, zero LDS-pipe ops. Lanes (l&7)==0 publish
//   part[t&1][q][w]. ONE barrier. Phase B: f4 gather, +px, ONE cos/lane;
//   R17-verified all-VALU collect broadcasts C0..C7; prefix/gates/LSTM
//   (R17-verified) for the single own column. part[] double-buffered;
//   single-barrier race pattern verified R15/R16.
// ---------------------------------------------------------------------------
__global__ __launch_bounds__(256, 1) void qlstm_seq(const float* __restrict__ hx,
                                                    const float* __restrict__ cx,
                                                    const float* __restrict__ Wp,
                                                    const float* __restrict__ Wg,
                                                    const float* __restrict__ bg,
                                                    const float* __restrict__ px,
                                                    float* __restrict__ out) {
    __shared__ float px_lds[(T_STEPS + 1) * 8];   // +8 pad for prefetch overrun
    __shared__ float part[2][8][4];               // [buf][q][wave] partial sums

    const int tid = threadIdx.x;
    const int w   = tid >> 6;     // wave id 0..3
    const int l   = tid & 63;     // lane
    const int b   = blockIdx.x;
    const int cg  = tid;          // this thread's column (h[cg], c[cg] in regs)
    const int qb  = l >> 3;       // q this lane carries after reduce-scatter

    // ---- weight loads (asm: non-rematerializable) ----
    float wph[8];                 // Wp[q][256+cg]
#pragma unroll
    for (int q = 0; q < 8; ++q) {
        const float* a = Wp + q * WPLD + DIN + cg;
        ASM_LOAD1(wph[q], a);
    }
    float4 WG0[4], WG1[4];        // Wg row (G*256+cg), floats 0..7
#pragma unroll
    for (int G = 0; G < 4; ++G) {
        const float* r = Wg + (size_t)(G * HID + cg) * 8;
        ASM_LOAD4(WG0[G], r);
        ASM_LOAD4(WG1[G], r + 4);
    }
    float bgc[4];                 // bg[G*256+cg]
#pragma unroll
    for (int G = 0; G < 4; ++G) {
        const float* a = bg + G * HID + cg;
        ASM_LOAD1(bgc[G], a);
    }

    // preload all px for this b (4096 floats = 1024 float4, 4 per thread)
    {
        const float4* pg = (const float4*)(px + (size_t)b * (T_STEPS * 8));
        float4* pl = (float4*)px_lds;
#pragma unroll
        for (int j = 0; j < 4; ++j) pl[j * 256 + tid] = pg[j * 256 + tid];
    }

    float hreg = hx[b * HID + cg];
    float c    = cx[b * HID + cg];

    asm volatile("s_waitcnt vmcnt(0)" ::: "memory");
    __builtin_amdgcn_sched_barrier(0);
    __syncthreads();   // px_lds ready (prologue only)

    float pxq = px_lds[qb];   // px[t=0][qb]

    float* outp = out + (size_t)b * HID + cg;

    for (int t = 0; t < T_STEPS; ++t) {
        // ---- phase A: 8 per-lane products, split-butterfly reduce-scatter ----
        const float p0 = hreg * wph[0], p1 = hreg * wph[1];
        const float p2 = hreg * wph[2], p3 = hreg * wph[3];
        const float p4 = hreg * wph[4], p5 = hreg * wph[5];
        const float p6 = hreg * wph[6], p7 = hreg * wph[7];

        // level xor32: keep 4 values (v bit2 = lane bit5), add partner's same-v
        const bool h5 = (l & 32) != 0;
        const float s0 = (h5 ? p4 : p0) + lane_xor32(h5 ? p0 : p4, l);
        const float s1 = (h5 ? p5 : p1) + lane_xor32(h5 ? p1 : p5, l);
        const float s2 = (h5 ? p6 : p2) + lane_xor32(h5 ? p2 : p6, l);
        const float s3 = (h5 ? p7 : p3) + lane_xor32(h5 ? p3 : p7, l);
        // level xor16: keep 2 (v bit1 = lane bit4)
        const bool h4b = (l & 16) != 0;
        const float u0 = (h4b ? s2 : s0) + lane_xor16(h4b ? s0 : s2, l);
        const float u1 = (h4b ? s3 : s1) + lane_xor16(h4b ? s1 : s3, l);
        // level xor8 (ror8 == exact xor8 in row16): keep 1 (v bit0 = lane bit3)
        const bool h3b = (l & 8) != 0;
        float v = (h3b ? u1 : u0) + dppmov<0x128>(h3b ? u0 : u1);
        // symmetric butterfly over bits 0..2 (value index l>>3 invariant)
        v += dppmov<0xB1>(v);            // xor1
        v += dppmov<0x4E>(v);            // xor2
        v += lane_xor4(v, l);            // xor4 (direction-fixed)

        // publish: one lane per 8-group writes its wave's partial for q=l>>3
        if ((l & 7) == 0) part[t & 1][qb][w] = v;

        STEP_BARRIER();   // the ONLY barrier per step

        // ---- phase B: gather 4 waves' partials, cos, collect, gates, LSTM ----
        const float4 f4 = *(const float4*)&part[t & 1][qb][0];
        const float S  = ((f4.x + f4.y) + (f4.z + f4.w)) + pxq;
        const float cw = __cosf(S);          // ONE cos per lane (its q=qb)

        pxq = px_lds[(t + 1) * 8 + qb];      // prefetch next px (off-path)

        // R17-verified all-VALU butterfly-collect: all 8 C's into every lane
        const float o8 = dppmov<0x128>(cw);
        const float x0 = (l & 8) ? o8 : cw;
        const float x1 = (l & 8) ? cw : o8;
        const float y0 = lane_xor16(x0, l), y1 = lane_xor16(x1, l);
        const float b0 = (l & 16) ? y0 : x0;
        const float b1 = (l & 16) ? y1 : x1;
        const float b2 = (l & 16) ? x0 : y0;
        const float b3 = (l & 16) ? x1 : y1;
        const float z0 = lane_xor32(b0, l), z1 = lane_xor32(b1, l);
        const float z2 = lane_xor32(b2, l), z3 = lane_xor32(b3, l);
        const float C0 = (l & 32) ? z0 : b0;
        const float C1 = (l & 32) ? z1 : b1;
        const float C2 = (l & 32) ? z2 : b2;
        const float C3 = (l & 32) ? z3 : b3;
        const float C4 = (l & 32) ? b0 : z0;
        const float C5 = (l & 32) ? b1 : z1;
        const float C6 = (l & 32) ? b2 : z2;
        const float C7 = (l & 32) ? b3 : z3;

        // prefix products: qo[0]=C1..C7, qo[k>=1]=C0..Ck
        const float d01 = C0 * C1, d23 = C2 * C3, d45 = C4 * C5, d67 = C6 * C7;
        float qo[8];
        qo[1] = d01;
        qo[2] = d01 * C2;
        qo[3] = d01 * d23;
        qo[4] = qo[3] * C4;
        qo[5] = qo[3] * d45;
        qo[6] = qo[5] * C6;
        qo[7] = qo[5] * d67;
        qo[0] = (C1 * d23) * (d45 * d67);

        // gates for this thread's single column (R17-verified tree)
        float gf, gi, gg, go;
        {
            float a0, a1;
            a0 = fmaf(WG0[0].x, qo[0], bgc[0]);  a0 = fmaf(WG0[0].y, qo[1], a0);
            a0 = fmaf(WG0[0].z, qo[2], a0);      a0 = fmaf(WG0[0].w, qo[3], a0);
            a1 = WG1[0].x * qo[4];               a1 = fmaf(WG1[0].y, qo[5], a1);
            a1 = fmaf(WG1[0].z, qo[6], a1);      a1 = fmaf(WG1[0].w, qo[7], a1);
            gf = a0 + a1;
            a0 = fmaf(WG0[1].x, qo[0], bgc[1]);  a0 = fmaf(WG0[1].y, qo[1], a0);
            a0 = fmaf(WG0[1].z, qo[2], a0);      a0 = fmaf(WG0[1].w, qo[3], a0);
            a1 = WG1[1].x * qo[4];               a1 = fmaf(WG1[1].y, qo[5], a1);
            a1 = fmaf(WG1[1].z, qo[6], a1);      a1 = fmaf(WG1[1].w, qo[7], a1);
            gi = a0 + a1;
            a0 = fmaf(WG0[2].x, qo[0], bgc[2]);  a0 = fmaf(WG0[2].y, qo[1], a0);
            a0 = fmaf(WG0[2].z, qo[2], a0);      a0 = fmaf(WG0[2].w, qo[3], a0);
            a1 = WG1[2].x * qo[4];               a1 = fmaf(WG1[2].y, qo[5], a1);
            a1 = fmaf(WG1[2].z, qo[6], a1);      a1 = fmaf(WG1[2].w, qo[7], a1);
            gg = a0 + a1;
            a0 = fmaf(WG0[3].x, qo[0], bgc[3]);  a0 = fmaf(WG0[3].y, qo[1], a0);
            a0 = fmaf(WG0[3].z, qo[2], a0);      a0 = fmaf(WG0[3].w, qo[3], a0);
            a1 = WG1[3].x * qo[4];               a1 = fmaf(WG1[3].y, qo[5], a1);
            a1 = fmaf(WG1[3].z, qo[6], a1);      a1 = fmaf(WG1[3].w, qo[7], a1);
            go = a0 + a1;
        }

        // LSTM pointwise (inf-safe parallel form, R12/R19-verified)
        const float sf = rcp_f(1.f + __expf(-gf));
        const float si = rcp_f(1.f + __expf(-gi));
        const float so = rcp_f(1.f + __expf(-go));
        const float tg = 1.f - 2.f * rcp_f(__expf(2.f * gg) + 1.f);
        const float cn = fmaf(sf, c, si * tg);
        const float th = 1.f - 2.f * rcp_f(__expf(2.f * cn) + 1.f);
        const float h  = so * th;
        c = cn;

        *outp = h;                   // coalesced store; not drained at barrier
        outp += BATCH * HID;

        hreg = h;                    // h stays in register
    }

    const size_t base = (size_t)T_STEPS * BATCH * HID;
    out[base + b * HID + cg] = hreg;
    out[base + BATCH * HID + b * HID + cg] = c;
}

extern "C" void kernel_launch(void* const* d_in, const int* in_sizes, int n_in,
                              void* d_out, int out_size, void* d_ws, size_t ws_size,
                              hipStream_t stream) {
    const float* x   = (const float*)d_in[0];   // (512,128,256)
    const float* hx  = (const float*)d_in[1];   // (128,256)
    const float* cx  = (const float*)d_in[2];   // (128,256)
    const float* Wp  = (const float*)d_in[3];   // (8,512)
    const float* qp  = (const float*)d_in[4];   // (8,)
    const float* Wg  = (const float*)d_in[5];   // (1024,8)
    const float* bg  = (const float*)d_in[6];   // (1024,)
    float* out = (float*)d_out;
    float* px  = (float*)d_ws;                  // 128*512*8 floats = 2 MB

    qlstm_projx<<<(T_STEPS * BATCH) / 4, 256, 0, stream>>>(x, Wp, qp, px);
    qlstm_seq<<<BATCH, 256, 0, stream>>>(hx, cx, Wp, Wg, bg, px, out);
}

// Round 23
// 263.406 us; speedup vs baseline: 1.5480x; 1.1286x over previous
//
#include <hip/hip_runtime.h>

#ifndef __has_builtin
#define __has_builtin(x) 0
#endif

#define T_STEPS 512
#define BATCH   128
#define DIN     256
#define HID     256
#define WPLD    (DIN + HID)   // 512

typedef float v2f __attribute__((ext_vector_type(2)));

// Volatile asm loads: results are NOT rematerializable (cheap insurance).
#define ASM_LOAD4(dst, ptr) \
    asm volatile("global_load_dwordx4 %0, %1, off" : "=v"(dst) : "v"(ptr))
#define ASM_LOAD1(dst, ptr) \
    asm volatile("global_load_dword %0, %1, off" : "=v"(dst) : "v"(ptr))

// Barrier WITHOUT vmcnt drain (verified R11/R12): waits only LDS ops.
#define STEP_BARRIER() do {                                   \
    asm volatile("s_waitcnt lgkmcnt(0)" ::: "memory");        \
    __builtin_amdgcn_s_barrier();                             \
    __builtin_amdgcn_sched_barrier(0);                        \
} while (0)

// ---------------- cross-lane helpers (verified in passing runs) ----------------
template<int CTRL>
__device__ __forceinline__ float dppmov(float x) {
    // 0xB1=quad xor1, 0x4E=quad xor2, 0x124=row_ror:4, 0x128=row_ror:8
    return __int_as_float(__builtin_amdgcn_update_dpp(0, __float_as_int(x), CTRL, 0xF, 0xF, true));
}
template<int PAT>
__device__ __forceinline__ float swz(float x) {
    return __int_as_float(__builtin_amdgcn_ds_swizzle(__float_as_int(x), PAT));
}
__device__ __forceinline__ float lane_xor16(float v, int l) {
#if __has_builtin(__builtin_amdgcn_permlane16_swap)
    auto r = __builtin_amdgcn_permlane16_swap(__float_as_uint(v), __float_as_uint(v), false, false);
    return __uint_as_float((l & 16) ? r[0] : r[1]);
#else
    return swz<0x401F>(v);
#endif
}
__device__ __forceinline__ float lane_xor32(float v, int l) {
#if __has_builtin(__builtin_amdgcn_permlane32_swap)
    auto r = __builtin_amdgcn_permlane32_swap(__float_as_uint(v), __float_as_uint(v), false, false);
    return __uint_as_float((l & 32) ? r[0] : r[1]);
#else
    return __shfl_xor(v, 32);
#endif
}
__device__ __forceinline__ float rcp_f(float x) {
#if __has_builtin(__builtin_amdgcn_rcpf)
    return __builtin_amdgcn_rcpf(x);
#else
    return 1.0f / x;
#endif
}
__device__ __forceinline__ v2f fma2(v2f a, v2f b, v2f c) {   // v_pk_fma_f32 (R18-verified)
#if __has_builtin(__builtin_elementwise_fma)
    return __builtin_elementwise_fma(a, b, c);
#else
    return (v2f){fmaf(a.x, b.x, c.x), fmaf(a.y, b.y, c.y)};
#endif
}

// ---------------------------------------------------------------------------
// Kernel 1: px[b][t][q] = sum_d x[t,b,d]*Wp[q,d] + qp[q]   (unchanged, verified)
// ---------------------------------------------------------------------------
__global__ __launch_bounds__(256) void qlstm_projx(const float* __restrict__ x,
                                                   const float* __restrict__ Wp,
                                                   const float* __restrict__ qp,
                                                   float* __restrict__ px) {
    const int wave = threadIdx.x >> 6;
    const int lane = threadIdx.x & 63;
    const int row  = blockIdx.x * 4 + wave;       // row = t*BATCH + b

    const float4 xv = ((const float4*)(x + (size_t)row * DIN))[lane];
    float acc[8];
#pragma unroll
    for (int Q = 0; Q < 8; ++Q) {
        float4 w = ((const float4*)(Wp + Q * WPLD))[lane];
        acc[Q] = xv.x * w.x + xv.y * w.y + xv.z * w.z + xv.w * w.w;
    }
#pragma unroll
    for (int Q = 0; Q < 8; ++Q) {
        acc[Q] += dppmov<0xB1>(acc[Q]);
        acc[Q] += dppmov<0x4E>(acc[Q]);
        acc[Q] += swz<0x101F>(acc[Q]);
    }
    float p = acc[0];
#pragma unroll
    for (int j = 1; j < 8; ++j) p = ((lane & 7) == j) ? acc[j] : p;
    p += swz<0x201F>(p);
    p += swz<0x401F>(p);
    p += __shfl_xor(p, 32);
    if (lane < 8) {
        const int bb = row & (BATCH - 1);
        const int tt = row >> 7;
        px[(size_t)bb * (T_STEPS * 8) + tt * 8 + lane] = p + qp[lane];
    }
}

// ---------------------------------------------------------------------------
// Kernel 2: recurrence = R12's verified two-phase structure (262 us), with
// issue trims only: pk-fma proj dot, px added after the reduce (uniform add,
// no cndmask on chain head), pk-fma gates (R18-verified fma2). One row per
// block, 4 waves, wave w owns q=2w,2w+1; two STEP_BARRIERs per step.
// This is the empirical optimum of 10 structural variants (R8..R22).
// ---------------------------------------------------------------------------
__global__ __launch_bounds__(256, 1) void qlstm_seq(const float* __restrict__ hx,
                                                    const float* __restrict__ cx,
                                                    const float* __restrict__ Wp,
                                                    const float* __restrict__ Wg,
                                                    const float* __restrict__ bg,
                                                    const float* __restrict__ px,
                                                    float* __restrict__ out) {
    __shared__ float px_lds[(T_STEPS + 1) * 8];   // +8 pad for prefetch overrun
    __shared__ float hbuf[HID];                   // single-buffered h
    __shared__ float cq_lds[8];                   // single-buffered cos values

    const int tid = threadIdx.x;
    const int w   = tid >> 6;     // wave id 0..3 -> owns q=2w,2w+1
    const int l   = tid & 63;     // lane
    const int b   = blockIdx.x;
    const int cg  = tid;          // this thread's gate/LSTM column

    // ---- weight loads (asm: non-rematerializable) ----
    float4 wph0, wph1;            // Wp[2w][256+4l..], Wp[2w+1][256+4l..]
    {
        const float* a0 = Wp + (2 * w) * WPLD + DIN + 4 * l;
        const float* a1 = Wp + (2 * w + 1) * WPLD + DIN + 4 * l;
        ASM_LOAD4(wph0, a0);
        ASM_LOAD4(wph1, a1);
    }
    float4 WG0[4], WG1[4];        // Wg row (G*256+cg), floats 0..7
#pragma unroll
    for (int G = 0; G < 4; ++G) {
        const float* r = Wg + (size_t)(G * HID + cg) * 8;
        ASM_LOAD4(WG0[G], r);
        ASM_LOAD4(WG1[G], r + 4);
    }
    float bgc[4];                 // bg[G*256+cg]
#pragma unroll
    for (int G = 0; G < 4; ++G) {
        const float* a = bg + G * HID + cg;
        ASM_LOAD1(bgc[G], a);
    }

    // preload all px for this b (4096 floats = 1024 float4, 4 per thread)
    {
        const float4* pg = (const float4*)(px + (size_t)b * (T_STEPS * 8));
        float4* pl = (float4*)px_lds;
#pragma unroll
        for (int j = 0; j < 4; ++j) pl[j * 256 + tid] = pg[j * 256 + tid];
    }

    float c = cx[b * HID + cg];
    hbuf[tid] = hx[b * HID + tid];

    asm volatile("s_waitcnt vmcnt(0)" ::: "memory");
    __builtin_amdgcn_sched_barrier(0);
    __syncthreads();   // hbuf + px_lds ready (prologue only)

    // repack proj weights to v2f (one-time register moves)
    const v2f wA0 = (v2f){wph0.x, wph0.y}, wB0 = (v2f){wph0.z, wph0.w};
    const v2f wA1 = (v2f){wph1.x, wph1.y}, wB1 = (v2f){wph1.z, wph1.w};
    // repack gate weights to v2f pairs
    v2f wg2[4][4];
#pragma unroll
    for (int G = 0; G < 4; ++G) {
        wg2[G][0] = (v2f){WG0[G].x, WG0[G].y};
        wg2[G][1] = (v2f){WG0[G].z, WG0[G].w};
        wg2[G][2] = (v2f){WG1[G].x, WG1[G].y};
        wg2[G][3] = (v2f){WG1[G].z, WG1[G].w};
    }

    // prefetch this wave's px pair for t=0
    float2 pxp = *(const float2*)&px_lds[2 * w];

    float* outp = out + (size_t)b * HID + cg;
    float h = 0.f;

    for (int t = 0; t < T_STEPS; ++t) {
        // ---- phase 1: this wave's two q-dots over the full h ----
        const float4 h4 = *(const float4*)&hbuf[4 * l];
        const v2f hA = (v2f){h4.x, h4.y}, hB = (v2f){h4.z, h4.w};

        v2f a0 = hA * wA0;  a0 = fma2(hB, wB0, a0);
        v2f a1 = hA * wA1;  a1 = fma2(hB, wB1, a1);
        float v0 = a0.x + a0.y;
        float v1 = a1.x + a1.y;

        // verified butterfly allreduce (two interleaved chains)
        v0 += dppmov<0xB1>(v0);   v1 += dppmov<0xB1>(v1);    // xor1
        v0 += dppmov<0x4E>(v0);   v1 += dppmov<0x4E>(v1);    // xor2
        v0 += dppmov<0x124>(v0);  v1 += dppmov<0x124>(v1);   // ror4
        v0 += dppmov<0x128>(v0);  v1 += dppmov<0x128>(v1);   // ror8
        v0 += lane_xor16(v0, l);  v1 += lane_xor16(v1, l);
        v0 += lane_xor32(v0, l);  v1 += lane_xor32(v1, l);

        // px folded AFTER the reduce: uniform add, off the chain head
        const float cq0 = __cosf(v0 + pxp.x);
        const float cq1 = __cosf(v1 + pxp.y);
        if (l == 0) {
            *(float2*)&cq_lds[2 * w] = make_float2(cq0, cq1);
        }
        STEP_BARRIER();   // bar1: cq visible; separates h-read from h-write

        // ---- phase 2: gates/LSTM for this thread's column ----
        const float4 cqa = *(const float4*)&cq_lds[0];
        const float4 cqb = *(const float4*)&cq_lds[4];

        // prefetch px pair for t+1 (independent of cq)
        pxp = *(const float2*)&px_lds[(t + 1) * 8 + 2 * w];

        const float C0 = cqa.x, C1 = cqa.y, C2 = cqa.z, C3 = cqa.w;
        const float C4 = cqb.x, C5 = cqb.y, C6 = cqb.z, C7 = cqb.w;

        // prefix products: qo[0]=C1..C7, qo[k>=1]=C0..Ck
        const float d01 = C0 * C1, d23 = C2 * C3, d45 = C4 * C5, d67 = C6 * C7;
        const float q1 = d01;
        const float q2 = d01 * C2;
        const float q3 = d01 * d23;
        const float q4 = q3 * C4;
        const float q5 = q3 * d45;
        const float q6 = q5 * C6;
        const float q7 = q5 * d67;
        const float q0 = (C1 * d23) * (d45 * d67);

        const v2f qv[4] = {(v2f){q0, q1}, (v2f){q2, q3}, (v2f){q4, q5}, (v2f){q6, q7}};

        // gates: packed FMA (v_pk_fma_f32), 4 pk-fma + 1 add per gate
        float g[4];
#pragma unroll
        for (int G = 0; G < 4; ++G) {
            v2f acc = (v2f){bgc[G], 0.f};
            acc = fma2(wg2[G][0], qv[0], acc);
            acc = fma2(wg2[G][1], qv[1], acc);
            acc = fma2(wg2[G][2], qv[2], acc);
            acc = fma2(wg2[G][3], qv[3], acc);
            g[G] = acc.x + acc.y;
        }

        // LSTM pointwise, parallel form (inf-safe, no clamp) — as R12
        const float sf = rcp_f(1.f + __expf(-g[0]));
        const float si = rcp_f(1.f + __expf(-g[1]));
        const float so = rcp_f(1.f + __expf(-g[3]));
        const float tg = 1.f - 2.f * rcp_f(__expf(2.f * g[2]) + 1.f);
        const float cn = fmaf(sf, c, si * tg);
        const float th = 1.f - 2.f * rcp_f(__expf(2.f * cn) + 1.f);
        h = so * th;
        c = cn;

        *outp = h;                   // global store; not drained at barriers
        outp += BATCH * HID;

        hbuf[cg] = h;                // publish new h
        STEP_BARRIER();              // bar2: h visible; separates cq read/write
    }

    const size_t base = (size_t)T_STEPS * BATCH * HID;
    out[base + b * HID + cg] = h;
    out[base + BATCH * HID + b * HID + cg] = c;
}

extern "C" void kernel_launch(void* const* d_in, const int* in_sizes, int n_in,
                              void* d_out, int out_size, void* d_ws, size_t ws_size,
                              hipStream_t stream) {
    const float* x   = (const float*)d_in[0];   // (512,128,256)
    const float* hx  = (const float*)d_in[1];   // (128,256)
    const float* cx  = (const float*)d_in[2];   // (128,256)
    const float* Wp  = (const float*)d_in[3];   // (8,512)
    const float* qp  = (const float*)d_in[4];   // (8,)
    const float* Wg  = (const float*)d_in[5];   // (1024,8)
    const float* bg  = (const float*)d_in[6];   // (1024,)
    float* out = (float*)d_out;
    float* px  = (float*)d_ws;                  // 128*512*8 floats = 2 MB

    qlstm_projx<<<(T_STEPS * BATCH) / 4, 256, 0, stream>>>(x, Wp, qp, px);
    qlstm_seq<<<BATCH, 256, 0, stream>>>(hx, cx, Wp, Wg, bg, px, out);
}